// Round 9
// baseline (204.154 us; speedup 1.0000x reference)
//
#include <hip/hip_runtime.h>

#define SBD   384
#define NCATS 64
#define EMB   48
#define HT    256
#define HC    128

typedef __attribute__((ext_vector_type(8))) short short8;
typedef __attribute__((ext_vector_type(4))) float f32x4;

__device__ __forceinline__ short f2bf(float x) {
    union { float f; unsigned u; } v; v.f = x;
    unsigned r = v.u + 0x7FFF + ((v.u >> 16) & 1);   // RNE
    return (short)(r >> 16);
}

__device__ __forceinline__ short8 cvt8(float4 a, float4 b) {
    short8 h;
    h[0] = f2bf(a.x); h[1] = f2bf(a.y); h[2] = f2bf(a.z); h[3] = f2bf(a.w);
    h[4] = f2bf(b.x); h[5] = f2bf(b.y); h[6] = f2bf(b.z); h[7] = f2bf(b.w);
    return h;
}

__device__ __forceinline__ void glds16(const void* g, void* l) {
    __builtin_amdgcn_global_load_lds((const __attribute__((address_space(1))) void*)g,
                                     (__attribute__((address_space(3))) void*)l, 16, 0, 0);
}

#define MFMA(a, b, c) __builtin_amdgcn_mfma_f32_16x16x32_bf16((a), (b), (c), 0, 0, 0)

// ---------------------------------------------------------------------------
// Prep: iT1 LINEAR [256n][384k] bf16 (K1 reads B-frags into registers).
// iK2 = [iT2 swz 24KB | iC1 swz 16KB | iC2 swz 12KB] (52KB LDS image for K2).
// swz: byte ^= (n&7)<<4 within each row-of-contiguous-k.
// ---------------------------------------------------------------------------
__global__ void prep_weights(const float* __restrict__ Wt1, const float* __restrict__ Wt2,
                             const float* __restrict__ Wc1, const float* __restrict__ Wc2,
                             char* __restrict__ iT1, char* __restrict__ iK2) {
    int t = blockIdx.x * blockDim.x + threadIdx.x;
    int stride = gridDim.x * blockDim.x;
    for (int g = t; g < 256 * 48; g += stride) {       // Wt1 [384k][256n]
        int n = g / 48, k0 = (g - n * 48) * 8;
        short8 v;
        #pragma unroll
        for (int j = 0; j < 8; ++j) v[j] = f2bf(Wt1[(size_t)(k0 + j) * HT + n]);
        *(short8*)(iT1 + (size_t)n * 768 + k0 * 2) = v;
    }
    for (int g = t; g < 48 * 32; g += stride) {        // Wt2 [256k][48n]
        int n = g / 32, k0 = (g - n * 32) * 8;
        short8 v;
        #pragma unroll
        for (int j = 0; j < 8; ++j) v[j] = f2bf(Wt2[(size_t)(k0 + j) * EMB + n]);
        *(short8*)(iK2 + ((n * 512 + k0 * 2) ^ ((n & 7) << 4))) = v;
    }
    for (int g = t; g < 128 * 8; g += stride) {        // Wc1 [64k][128n]
        int n = g / 8, k0 = (g - n * 8) * 8;
        short8 v;
        #pragma unroll
        for (int j = 0; j < 8; ++j) v[j] = f2bf(Wc1[(size_t)(k0 + j) * HC + n]);
        *(short8*)(iK2 + 24576 + ((n * 128 + k0 * 2) ^ ((n & 7) << 4))) = v;
    }
    for (int g = t; g < 48 * 16; g += stride) {        // Wc2 [128k][48n]
        int n = g / 16, k0 = (g - n * 16) * 8;
        short8 v;
        #pragma unroll
        for (int j = 0; j < 8; ++j) v[j] = f2bf(Wc2[(size_t)(k0 + j) * EMB + n]);
        *(short8*)(iK2 + 40960 + ((n * 256 + k0 * 2) ^ ((n & 7) << 4))) = v;
    }
}

// ---------------------------------------------------------------------------
// K1: H1t = relu(sbert @ Wt1 + bt1) -> bf16 [nbooks][256].
// 512 persistent blocks (flavor = n-half, seq = m-offset), 512 thr = 8 waves.
// Wave owns 16 cols; B = 12 short8 in REGISTERS loaded once (48 VGPR).
// A: 32-book tiles, reg-staged fp32->bf16 (cvt ONCE per element), LDS dbuf
// 2x24KB swz. Barriers: lgkmcnt(0)+s_barrier only -- prefetch loads stay in
// flight across barriers. Loop 2-unrolled so ring indices are compile-time.
// ---------------------------------------------------------------------------
__global__ __launch_bounds__(512, 4) void k1_l1txt(
    const float* __restrict__ sbert, const char* __restrict__ iT1,
    const float* __restrict__ bt1, unsigned short* __restrict__ H1t, int nt1)
{
    __shared__ char lds[49152];

    const int t  = threadIdx.x;
    const int w  = t >> 6;
    const int l  = t & 63;
    const int lr = l & 15;
    const int lg = l >> 4;
    const int flavor  = (int)(blockIdx.x & 1);
    const int seq     = (int)(blockIdx.x >> 1);
    const int colbase = flavor * 128 + w * 16;

    // B-frags once (L2-resident image)
    short8 B[12];
    #pragma unroll
    for (int ks = 0; ks < 12; ++ks)
        B[ks] = *(const short8*)(iT1 + (size_t)(colbase + lr) * 768 + (ks * 32 + lg * 8) * 2);
    const float bias = bt1[colbase + lr];

    // staging map: thread handles 3 short8-granules of the 32x384 tile
    int rowj[3], c8j[3], dstj[3];
    #pragma unroll
    for (int j = 0; j < 3; ++j) {
        int f8 = t + 512 * j;
        int row = f8 / 48, c8 = f8 - row * 48;
        rowj[j] = row; c8j[j] = c8;
        dstj[j] = (row * 768 + c8 * 16) ^ ((row & 7) << 4);
    }

    float4 ra[3][2], rb[3][2];
    #define LOADR(tile, r)                                                        \
        { _Pragma("unroll")                                                       \
          for (int j = 0; j < 3; ++j) {                                           \
              const float* p = sbert + (size_t)((tile) * 32 + rowj[j]) * SBD + c8j[j] * 8; \
              r[j][0] = *(const float4*)p; r[j][1] = *(const float4*)(p + 4);     \
          } }
    #define WRITEB(r, bufoff)                                                     \
        { _Pragma("unroll")                                                       \
          for (int j = 0; j < 3; ++j)                                             \
              *(short8*)(lds + (bufoff) + dstj[j]) = cvt8(r[j][0], r[j][1]); }

    const int sw = (lr & 7) << 4;
    #define COMPUTE(tile, bufoff)                                                 \
        { f32x4 a0 = (f32x4){bias, bias, bias, bias}, a1 = a0;                    \
          _Pragma("unroll")                                                       \
          for (int ks = 0; ks < 12; ++ks) {                                       \
              short8 f0 = *(const short8*)(lds + (bufoff) + ((lr * 768 + (ks * 32 + lg * 8) * 2) ^ sw));       \
              short8 f1 = *(const short8*)(lds + (bufoff) + (((16 + lr) * 768 + (ks * 32 + lg * 8) * 2) ^ sw));\
              a0 = MFMA(f0, B[ks], a0);                                           \
              a1 = MFMA(f1, B[ks], a1);                                           \
          }                                                                       \
          _Pragma("unroll")                                                       \
          for (int r = 0; r < 4; ++r) {                                           \
              int r0 = (tile) * 32 + lg * 4 + r;                                  \
              H1t[(size_t)r0 * 256 + colbase + lr]        = (unsigned short)f2bf(fmaxf(a0[r], 0.f)); \
              H1t[(size_t)(r0 + 16) * 256 + colbase + lr] = (unsigned short)f2bf(fmaxf(a1[r], 0.f)); \
          } }

    #define KBAR  asm volatile("s_waitcnt lgkmcnt(0)" ::: "memory");              \
                  __builtin_amdgcn_sched_barrier(0);                              \
                  __builtin_amdgcn_s_barrier();

    // prologue
    LOADR(seq, ra);
    WRITEB(ra, 0);
    const int t1 = seq + 256;
    if (t1 < nt1) LOADR(t1, rb);
    KBAR;

    for (int te = seq; te < nt1; te += 512) {
        const int to = te + 256, tn_e = te + 512, tn_o = to + 512;
        if (tn_e < nt1) LOADR(tn_e, ra);      // issue-early (crosses barriers)
        COMPUTE(te, 0);
        if (to < nt1) WRITEB(rb, 24576);      // write-late (other buffer)
        KBAR;
        if (to >= nt1) break;
        if (tn_o < nt1) LOADR(tn_o, rb);
        COMPUTE(to, 24576);
        if (tn_e < nt1) WRITEB(ra, 0);
        KBAR;
    }
    #undef LOADR
    #undef WRITEB
    #undef COMPUTE
    #undef KBAR
}

// ---------------------------------------------------------------------------
// K2: fused tail. 512 blocks x 512 thr (8 waves). Wave owns one 16-book group
// end-to-end (no barriers in the loop): L2txt (A from global H1t) -> catL1
// (mh regs) -> H1c (wave-private LDS, lgkm only) -> catL2 -> norm -> E.
// LDS 84KB: weights 52K (glds once) + 8 x 4K H1c.
// ---------------------------------------------------------------------------
__global__ __launch_bounds__(512, 2) void k2_tail(
    const unsigned short* __restrict__ H1t, const float* __restrict__ mh,
    const char* __restrict__ iK2,
    const float* __restrict__ bt2, const float* __restrict__ bc1,
    const float* __restrict__ bc2, float* __restrict__ E, int ngroups)
{
    __shared__ char lds[86016];   // 52K weights @0 ; 8 x 4K H1c @53248

    const int t  = threadIdx.x;
    const int w  = t >> 6;
    const int l  = t & 63;
    const int lr = l & 15;
    const int lg = l >> 4;

    #pragma unroll
    for (int j = 0; j < 7; ++j) {
        int gi = t + j * 512;
        if (gi < 3328) glds16(iK2 + gi * 16, lds + gi * 16);
    }
    asm volatile("s_waitcnt vmcnt(0)" ::: "memory");
    __syncthreads();

    const int sw = (lr & 7) << 4;
    char* hc = lds + 53248 + w * 4096;
    const int wid = (int)blockIdx.x * 8 + w;

    for (int g = wid; g < ngroups; g += 4096) {
        const char* hrow = (const char*)H1t + (size_t)(g * 16 + lr) * 512;

        // ---- L2 txt: K=256, A-frags straight from global (L2/L3) ----
        f32x4 acct[3];
        #pragma unroll
        for (int nt = 0; nt < 3; ++nt) { float b = bt2[nt * 16 + lr]; acct[nt] = (f32x4){b, b, b, b}; }
        #pragma unroll
        for (int ks = 0; ks < 8; ++ks) {
            short8 af = *(const short8*)(hrow + (ks * 32 + lg * 8) * 2);
            #pragma unroll
            for (int nt = 0; nt < 3; ++nt) {
                short8 bf = *(const short8*)(lds + (((nt * 16 + lr) * 512 + (ks * 32 + lg * 8) * 2) ^ sw));
                acct[nt] = MFMA(af, bf, acct[nt]);
            }
        }

        // ---- cat L1: mh (own rows, cvt once) @ Wc1 ----
        const float* mp = mh + (size_t)(g * 16 + lr) * NCATS + lg * 8;
        float4 m0 = *(const float4*)(mp),      m1 = *(const float4*)(mp + 4);
        float4 m2 = *(const float4*)(mp + 32), m3 = *(const float4*)(mp + 36);
        short8 c0 = cvt8(m0, m1), c1 = cvt8(m2, m3);
        f32x4 accc[8];
        #pragma unroll
        for (int nt = 0; nt < 8; ++nt) { float b = bc1[nt * 16 + lr]; accc[nt] = (f32x4){b, b, b, b}; }
        #pragma unroll
        for (int nt = 0; nt < 8; ++nt) {
            short8 b0 = *(const short8*)(lds + 24576 + (((nt * 16 + lr) * 128 + lg * 16) ^ sw));
            short8 b1 = *(const short8*)(lds + 24576 + (((nt * 16 + lr) * 128 + 64 + lg * 16) ^ sw));
            accc[nt] = MFMA(c0, b0, accc[nt]);
            accc[nt] = MFMA(c1, b1, accc[nt]);
        }

        // ---- H1c: wave-private transpose through LDS ----
        #pragma unroll
        for (int nt = 0; nt < 8; ++nt)
            #pragma unroll
            for (int r = 0; r < 4; ++r) {
                int rr = lg * 4 + r;
                *(unsigned short*)(hc + ((rr * 256 + (nt * 16 + lr) * 2) ^ ((rr & 7) << 4))) =
                    (unsigned short)f2bf(fmaxf(accc[nt][r], 0.f));
            }
        asm volatile("s_waitcnt lgkmcnt(0)" ::: "memory");
        __builtin_amdgcn_sched_barrier(0);

        // ---- cat L2: K=128 ----
        f32x4 acc2[3];
        #pragma unroll
        for (int nt = 0; nt < 3; ++nt) { float b = bc2[nt * 16 + lr]; acc2[nt] = (f32x4){b, b, b, b}; }
        #pragma unroll
        for (int ks = 0; ks < 4; ++ks) {
            short8 af = *(const short8*)(hc + ((lr * 256 + (ks * 32 + lg * 8) * 2) ^ sw));
            #pragma unroll
            for (int nt = 0; nt < 3; ++nt) {
                short8 bf = *(const short8*)(lds + 40960 + (((nt * 16 + lr) * 256 + (ks * 32 + lg * 8) * 2) ^ sw));
                acc2[nt] = MFMA(af, bf, acc2[nt]);
            }
        }

        // ---- combine, l2norm, store E ----
        f32x4 comb[3];
        #pragma unroll
        for (int nt = 0; nt < 3; ++nt)
            #pragma unroll
            for (int r = 0; r < 4; ++r) comb[nt][r] = 3.0f * acc2[nt][r] + acct[nt][r];
        #pragma unroll
        for (int r = 0; r < 4; ++r) {
            float ss = comb[0][r] * comb[0][r] + comb[1][r] * comb[1][r] + comb[2][r] * comb[2][r];
            ss += __shfl_xor(ss, 1); ss += __shfl_xor(ss, 2);
            ss += __shfl_xor(ss, 4); ss += __shfl_xor(ss, 8);
            float rn = rsqrtf(fmaxf(ss, 1e-12f));
            int grow = g * 16 + lg * 4 + r;
            #pragma unroll
            for (int nt = 0; nt < 3; ++nt)
                E[(size_t)grow * EMB + nt * 16 + lr] = comb[nt][r] * rn;
        }
    }
}

// ---------------------------------------------------------------------------
// Scoring: 16 lanes/sample, 3 dims/lane, shuffle-reduce.
// ---------------------------------------------------------------------------
__global__ __launch_bounds__(256) void score_kernel(
    const int* __restrict__ user_idx, const int* __restrict__ loc_idx,
    const int* __restrict__ pos_idx,  const int* __restrict__ neg_idx,
    const float* __restrict__ ucat, const float* __restrict__ utxt,
    const float* __restrict__ lcat, const float* __restrict__ ltxt,
    const float* __restrict__ E, float* __restrict__ out, int Bn)
{
    const int t    = threadIdx.x;
    const int lane = t & 15;
    const int s    = blockIdx.x * 16 + (t >> 4);
    if (s >= Bn) return;

    const int ui = user_idx[s];
    const int li = loc_idx[s];
    const int pi = pos_idx[s];
    const int ni = neg_idx[s];

    const int d0 = lane * 3;
    const float* uc = ucat + (size_t)ui * EMB + d0;
    const float* ut = utxt + (size_t)ui * EMB + d0;
    const float* lc = lcat + (size_t)li * EMB + d0;
    const float* lt = ltxt + (size_t)li * EMB + d0;
    const float* pp = E + (size_t)pi * EMB + d0;
    const float* nn = E + (size_t)ni * EMB + d0;

    float u0 = 3.0f * (uc[0] + lc[0]) + (ut[0] + lt[0]);
    float u1 = 3.0f * (uc[1] + lc[1]) + (ut[1] + lt[1]);
    float u2 = 3.0f * (uc[2] + lc[2]) + (ut[2] + lt[2]);

    float usq = u0 * u0 + u1 * u1 + u2 * u2;
    float ps  = u0 * pp[0] + u1 * pp[1] + u2 * pp[2];
    float ns  = u0 * nn[0] + u1 * nn[1] + u2 * nn[2];

    #pragma unroll
    for (int m = 1; m < 16; m <<= 1) {
        usq += __shfl_xor(usq, m);
        ps  += __shfl_xor(ps, m);
        ns  += __shfl_xor(ns, m);
    }

    if (lane == 0) {
        const float inv = rsqrtf(fmaxf(usq, 1e-12f)) * 20.0f;  // /TEMP
        out[2 * (size_t)s + 0] = ps * inv;
        out[2 * (size_t)s + 1] = ns * inv;
    }
}

extern "C" void kernel_launch(void* const* d_in, const int* in_sizes, int n_in,
                              void* d_out, int out_size, void* d_ws, size_t ws_size,
                              hipStream_t stream) {
    const int*   user_idx = (const int*)d_in[0];
    const int*   loc_idx  = (const int*)d_in[1];
    const int*   pos_idx  = (const int*)d_in[2];
    const int*   neg_idx  = (const int*)d_in[3];
    const float* ucat     = (const float*)d_in[4];
    const float* utxt     = (const float*)d_in[5];
    const float* lcat     = (const float*)d_in[6];
    const float* ltxt     = (const float*)d_in[7];
    const float* sbert    = (const float*)d_in[8];
    const float* mh       = (const float*)d_in[9];
    const float* Wc1      = (const float*)d_in[10];
    const float* bc1      = (const float*)d_in[11];
    const float* Wc2      = (const float*)d_in[12];
    const float* bc2      = (const float*)d_in[13];
    const float* Wt1      = (const float*)d_in[14];
    const float* bt1      = (const float*)d_in[15];
    const float* Wt2      = (const float*)d_in[16];
    const float* bt2      = (const float*)d_in[17];

    const int Bn      = in_sizes[0];
    const int nbooks  = in_sizes[8] / SBD;        // 100000
    const int nt1     = nbooks / 32;              // 3125 (exact)
    const int ngroups = nbooks / 16;              // 6250 (exact)

    char* ws = (char*)d_ws;
    float* E = (float*)ws;
    size_t off = ((size_t)nbooks * EMB * 4 + 255) & ~(size_t)255;
    char* iT1 = ws + off;  off += 196608;
    char* iK2 = ws + off;  off += 53248;
    off = (off + 511) & ~(size_t)511;
    unsigned short* H1t = (unsigned short*)(ws + off);   // [nbooks][256] bf16

    hipLaunchKernelGGL(prep_weights, dim3(64), dim3(256), 0, stream,
                       Wt1, Wt2, Wc1, Wc2, iT1, iK2);

    hipLaunchKernelGGL(k1_l1txt, dim3(512), dim3(512), 0, stream,
                       sbert, iT1, bt1, H1t, nt1);

    hipLaunchKernelGGL(k2_tail, dim3(512), dim3(512), 0, stream,
                       H1t, mh, iK2, bt2, bc1, bc2, E, ngroups);

    const int nblocksB = (Bn + 15) / 16;
    hipLaunchKernelGGL(score_kernel, dim3(nblocksB), dim3(256), 0, stream,
                       user_idx, loc_idx, pos_idx, neg_idx,
                       ucat, utxt, lcat, ltxt, E, (float*)d_out, Bn);
}

// Round 10
// 123.599 us; speedup vs baseline: 1.6517x; 1.6517x over previous
//
#include <hip/hip_runtime.h>

#define SBD   384
#define NCATS 64
#define EMB   48
#define HT    256
#define HC    128

typedef __attribute__((ext_vector_type(8))) short short8;
typedef __attribute__((ext_vector_type(4))) float f32x4;

__device__ __forceinline__ short f2bf(float x) {
    union { float f; unsigned u; } v; v.f = x;
    unsigned r = v.u + 0x7FFF + ((v.u >> 16) & 1);   // RNE
    return (short)(r >> 16);
}

__device__ __forceinline__ short8 cvt8(float4 a, float4 b) {
    short8 h;
    h[0] = f2bf(a.x); h[1] = f2bf(a.y); h[2] = f2bf(a.z); h[3] = f2bf(a.w);
    h[4] = f2bf(b.x); h[5] = f2bf(b.y); h[6] = f2bf(b.z); h[7] = f2bf(b.w);
    return h;
}

__device__ __forceinline__ void glds16(const void* g, void* l) {
    __builtin_amdgcn_global_load_lds((const __attribute__((address_space(1))) void*)g,
                                     (__attribute__((address_space(3))) void*)l, 16, 0, 0);
}

#define MFMA(a, b, c) __builtin_amdgcn_mfma_f32_16x16x32_bf16((a), (b), (c), 0, 0, 0)

// ---------------------------------------------------------------------------
// Prep.
// iT1: 12 chunks of [256n][32k] bf16 (16KB each), rows (64B) pre-swizzled
//      byte ^= (n&7)<<4  -- glds'd linearly into the encoder's B dbuf.
// iK2: [iT2 [48][256] swz 24KB | iC1 [128][64] swz 16KB | iC2 [48][128] swz
//      12KB] = 52KB tail-weight image.
// ---------------------------------------------------------------------------
__global__ void prep_weights(const float* __restrict__ Wt1, const float* __restrict__ Wt2,
                             const float* __restrict__ Wc1, const float* __restrict__ Wc2,
                             char* __restrict__ iT1, char* __restrict__ iK2) {
    int t = blockIdx.x * blockDim.x + threadIdx.x;
    int stride = gridDim.x * blockDim.x;
    for (int g = t; g < 256 * 48; g += stride) {       // Wt1 [384k][256n]
        int n = g / 48, k0 = (g - n * 48) * 8;
        int c = k0 >> 5, kin = k0 & 31;
        short8 v;
        #pragma unroll
        for (int j = 0; j < 8; ++j) v[j] = f2bf(Wt1[(size_t)(k0 + j) * HT + n]);
        *(short8*)(iT1 + (size_t)c * 16384 + ((n * 64 + kin * 2) ^ ((n & 7) << 4))) = v;
    }
    for (int g = t; g < 48 * 32; g += stride) {        // Wt2 [256k][48n]
        int n = g / 32, k0 = (g - n * 32) * 8;
        short8 v;
        #pragma unroll
        for (int j = 0; j < 8; ++j) v[j] = f2bf(Wt2[(size_t)(k0 + j) * EMB + n]);
        *(short8*)(iK2 + ((n * 512 + k0 * 2) ^ ((n & 7) << 4))) = v;
    }
    for (int g = t; g < 128 * 8; g += stride) {        // Wc1 [64k][128n]
        int n = g / 8, k0 = (g - n * 8) * 8;
        short8 v;
        #pragma unroll
        for (int j = 0; j < 8; ++j) v[j] = f2bf(Wc1[(size_t)(k0 + j) * HC + n]);
        *(short8*)(iK2 + 24576 + ((n * 128 + k0 * 2) ^ ((n & 7) << 4))) = v;
    }
    for (int g = t; g < 48 * 16; g += stride) {        // Wc2 [128k][48n]
        int n = g / 16, k0 = (g - n * 16) * 8;
        short8 v;
        #pragma unroll
        for (int j = 0; j < 8; ++j) v[j] = f2bf(Wc2[(size_t)(k0 + j) * EMB + n]);
        *(short8*)(iK2 + 40960 + ((n * 256 + k0 * 2) ^ ((n & 7) << 4))) = v;
    }
}

// ---------------------------------------------------------------------------
// Fused encoder: 128 books/block, 782 blocks, 512 thr (8 waves, 2m x 4n).
// LDS map (148KB, 1 block/CU):
//   L1 : A bf16 [128][384] swz @0 (96K) ; B dbuf 2x16K @98304
//   tail: H1t [128][256] swz @0 (64K) ; H1c 8 x 4K @65536 ;
//         weights 52K @98304 (glds'd after L1, overlays dead B)
// L1 loop: per chunk {glds next B ; 4 A + 4 B ds_read ; 16 MFMA ;
//   vmcnt(0)+lgkm(0)+barrier}. A staged ONCE up front (one HBM latency/block).
// No register rings anywhere -- only acc + frags (compiler-safe).
// ---------------------------------------------------------------------------
__global__ __launch_bounds__(512, 2) void encode_fused(
    const float* __restrict__ sbert, const float* __restrict__ mh,
    const char* __restrict__ iT1, const char* __restrict__ iK2,
    const float* __restrict__ bt1, const float* __restrict__ bt2,
    const float* __restrict__ bc1, const float* __restrict__ bc2,
    float* __restrict__ E, int nbooks)
{
    __shared__ char lds[151552];

    const int t  = threadIdx.x;
    const int w  = t >> 6;
    const int l  = t & 63;
    const int lr = l & 15;
    const int lg = l >> 4;
    const int book0 = (int)blockIdx.x * 128;
    const int mw = w >> 2, nw = w & 3;     // 2m x 4n wave grid
    const int sw = (lr & 7) << 4;

    // ---- tail mh loads (own group: books book0+w*16+lr) -- hidden under L1 ----
    float4 mf0, mf1, mf2, mf3;
    {
        const float* mp = mh + (size_t)min(book0 + w * 16 + lr, nbooks - 1) * NCATS + lg * 8;
        mf0 = *(const float4*)(mp);      mf1 = *(const float4*)(mp + 4);
        mf2 = *(const float4*)(mp + 32); mf3 = *(const float4*)(mp + 36);
    }

    // ---- A-stage: whole 128x384 tile -> bf16 swz LDS (12 granules/thread) ----
    #pragma unroll
    for (int j = 0; j < 12; ++j) {
        int G = t + 512 * j;
        int row = G / 48, c8 = G - row * 48;
        const float* p = sbert + (size_t)min(book0 + row, nbooks - 1) * SBD + c8 * 8;
        float4 a = *(const float4*)p, b = *(const float4*)(p + 4);
        *(short8*)(lds + ((row * 768 + c8 * 16) ^ ((row & 7) << 4))) = cvt8(a, b);
    }
    // ---- B chunk 0 ----
    #pragma unroll
    for (int j = 0; j < 2; ++j)
        glds16(iT1 + t * 16 + j * 8192, lds + 98304 + t * 16 + j * 8192);
    __syncthreads();

    // ---- L1: 12 chunks ----
    f32x4 acc[4][4];
    #pragma unroll
    for (int bi = 0; bi < 4; ++bi) {
        float b = bt1[nw * 64 + bi * 16 + lr];
        #pragma unroll
        for (int ai = 0; ai < 4; ++ai) acc[ai][bi] = (f32x4){b, b, b, b};
    }

    #pragma unroll
    for (int c = 0; c < 12; ++c) {
        const int cur = c & 1;
        if (c < 11) {
            #pragma unroll
            for (int j = 0; j < 2; ++j)
                glds16(iT1 + (size_t)(c + 1) * 16384 + t * 16 + j * 8192,
                       lds + 98304 + (cur ^ 1) * 16384 + t * 16 + j * 8192);
        }
        short8 Af[4], Bf[4];
        #pragma unroll
        for (int ai = 0; ai < 4; ++ai)
            Af[ai] = *(const short8*)(lds +
                (((mw * 64 + ai * 16 + lr) * 768 + (c * 32 + lg * 8) * 2) ^ sw));
        #pragma unroll
        for (int bi = 0; bi < 4; ++bi)
            Bf[bi] = *(const short8*)(lds + 98304 + cur * 16384 +
                (((nw * 64 + bi * 16 + lr) * 64 + lg * 16) ^ sw));
        #pragma unroll
        for (int ai = 0; ai < 4; ++ai)
            #pragma unroll
            for (int bi = 0; bi < 4; ++bi)
                acc[ai][bi] = MFMA(Af[ai], Bf[bi], acc[ai][bi]);
        asm volatile("s_waitcnt vmcnt(0) lgkmcnt(0)" ::: "memory");
        __builtin_amdgcn_sched_barrier(0);
        __builtin_amdgcn_s_barrier();
    }

    // ---- post-L1: issue tail weights (dead B region) + write H1t (dead A) ----
    #pragma unroll
    for (int j = 0; j < 7; ++j) {
        int gi = t + j * 512;
        if (gi < 3328) glds16(iK2 + gi * 16, lds + 98304 + gi * 16);
    }
    #pragma unroll
    for (int ai = 0; ai < 4; ++ai)
        #pragma unroll
        for (int bi = 0; bi < 4; ++bi)
            #pragma unroll
            for (int r = 0; r < 4; ++r) {
                int row = mw * 64 + ai * 16 + lg * 4 + r;
                int col = nw * 64 + bi * 16 + lr;
                *(unsigned short*)(lds + ((row * 512 + col * 2) ^ ((row & 7) << 4))) =
                    (unsigned short)f2bf(fmaxf(acc[ai][bi][r], 0.f));
            }
    asm volatile("s_waitcnt vmcnt(0) lgkmcnt(0)" ::: "memory");
    __builtin_amdgcn_sched_barrier(0);
    __builtin_amdgcn_s_barrier();

    // ================= tail: wave w owns books book0+16w .. +16 =================
    char* hc = lds + 65536 + w * 4096;

    // L2 txt: H1t rows 16w+lr, K=256
    f32x4 acct[3];
    #pragma unroll
    for (int nt = 0; nt < 3; ++nt) { float b = bt2[nt * 16 + lr]; acct[nt] = (f32x4){b, b, b, b}; }
    #pragma unroll
    for (int ks = 0; ks < 8; ++ks) {
        short8 af = *(const short8*)(lds +
            (((w * 16 + lr) * 512 + (ks * 32 + lg * 8) * 2) ^ sw));
        #pragma unroll
        for (int nt = 0; nt < 3; ++nt) {
            short8 bf = *(const short8*)(lds + 98304 +
                (((nt * 16 + lr) * 512 + (ks * 32 + lg * 8) * 2) ^ sw));
            acct[nt] = MFMA(af, bf, acct[nt]);
        }
    }

    // cat L1: mh regs @ Wc1 (K=64)
    short8 c0 = cvt8(mf0, mf1), c1 = cvt8(mf2, mf3);
    f32x4 accc[8];
    #pragma unroll
    for (int nt = 0; nt < 8; ++nt) { float b = bc1[nt * 16 + lr]; accc[nt] = (f32x4){b, b, b, b}; }
    #pragma unroll
    for (int nt = 0; nt < 8; ++nt) {
        short8 b0 = *(const short8*)(lds + 122880 + (((nt * 16 + lr) * 128 + lg * 16) ^ sw));
        short8 b1 = *(const short8*)(lds + 122880 + (((nt * 16 + lr) * 128 + 64 + lg * 16) ^ sw));
        accc[nt] = MFMA(c0, b0, accc[nt]);
        accc[nt] = MFMA(c1, b1, accc[nt]);
    }

    // H1c (wave-private)
    #pragma unroll
    for (int nt = 0; nt < 8; ++nt)
        #pragma unroll
        for (int r = 0; r < 4; ++r) {
            int rr = lg * 4 + r;
            *(unsigned short*)(hc + ((rr * 256 + (nt * 16 + lr) * 2) ^ ((rr & 7) << 4))) =
                (unsigned short)f2bf(fmaxf(accc[nt][r], 0.f));
        }
    asm volatile("s_waitcnt lgkmcnt(0)" ::: "memory");
    __builtin_amdgcn_sched_barrier(0);

    // cat L2: K=128
    f32x4 acc2[3];
    #pragma unroll
    for (int nt = 0; nt < 3; ++nt) { float b = bc2[nt * 16 + lr]; acc2[nt] = (f32x4){b, b, b, b}; }
    #pragma unroll
    for (int ks = 0; ks < 4; ++ks) {
        short8 af = *(const short8*)(hc + ((lr * 256 + (ks * 32 + lg * 8) * 2) ^ sw));
        #pragma unroll
        for (int nt = 0; nt < 3; ++nt) {
            short8 bf = *(const short8*)(lds + 139264 +
                (((nt * 16 + lr) * 256 + (ks * 32 + lg * 8) * 2) ^ sw));
            acc2[nt] = MFMA(af, bf, acc2[nt]);
        }
    }

    // combine, l2norm, store E
    f32x4 comb[3];
    #pragma unroll
    for (int nt = 0; nt < 3; ++nt)
        #pragma unroll
        for (int r = 0; r < 4; ++r) comb[nt][r] = 3.0f * acc2[nt][r] + acct[nt][r];
    #pragma unroll
    for (int r = 0; r < 4; ++r) {
        float ss = comb[0][r] * comb[0][r] + comb[1][r] * comb[1][r] + comb[2][r] * comb[2][r];
        ss += __shfl_xor(ss, 1); ss += __shfl_xor(ss, 2);
        ss += __shfl_xor(ss, 4); ss += __shfl_xor(ss, 8);
        float rn = rsqrtf(fmaxf(ss, 1e-12f));
        int grow = book0 + w * 16 + lg * 4 + r;
        if (grow < nbooks) {
            #pragma unroll
            for (int nt = 0; nt < 3; ++nt)
                E[(size_t)grow * EMB + nt * 16 + lr] = comb[nt][r] * rn;
        }
    }
}

// ---------------------------------------------------------------------------
// Scoring: 16 lanes/sample, 3 dims/lane, shuffle-reduce.
// ---------------------------------------------------------------------------
__global__ __launch_bounds__(256) void score_kernel(
    const int* __restrict__ user_idx, const int* __restrict__ loc_idx,
    const int* __restrict__ pos_idx,  const int* __restrict__ neg_idx,
    const float* __restrict__ ucat, const float* __restrict__ utxt,
    const float* __restrict__ lcat, const float* __restrict__ ltxt,
    const float* __restrict__ E, float* __restrict__ out, int Bn)
{
    const int t    = threadIdx.x;
    const int lane = t & 15;
    const int s    = blockIdx.x * 16 + (t >> 4);
    if (s >= Bn) return;

    const int ui = user_idx[s];
    const int li = loc_idx[s];
    const int pi = pos_idx[s];
    const int ni = neg_idx[s];

    const int d0 = lane * 3;
    const float* uc = ucat + (size_t)ui * EMB + d0;
    const float* ut = utxt + (size_t)ui * EMB + d0;
    const float* lc = lcat + (size_t)li * EMB + d0;
    const float* lt = ltxt + (size_t)li * EMB + d0;
    const float* pp = E + (size_t)pi * EMB + d0;
    const float* nn = E + (size_t)ni * EMB + d0;

    float u0 = 3.0f * (uc[0] + lc[0]) + (ut[0] + lt[0]);
    float u1 = 3.0f * (uc[1] + lc[1]) + (ut[1] + lt[1]);
    float u2 = 3.0f * (uc[2] + lc[2]) + (ut[2] + lt[2]);

    float usq = u0 * u0 + u1 * u1 + u2 * u2;
    float ps  = u0 * pp[0] + u1 * pp[1] + u2 * pp[2];
    float ns  = u0 * nn[0] + u1 * nn[1] + u2 * nn[2];

    #pragma unroll
    for (int m = 1; m < 16; m <<= 1) {
        usq += __shfl_xor(usq, m);
        ps  += __shfl_xor(ps, m);
        ns  += __shfl_xor(ns, m);
    }

    if (lane == 0) {
        const float inv = rsqrtf(fmaxf(usq, 1e-12f)) * 20.0f;  // /TEMP
        out[2 * (size_t)s + 0] = ps * inv;
        out[2 * (size_t)s + 1] = ns * inv;
    }
}

extern "C" void kernel_launch(void* const* d_in, const int* in_sizes, int n_in,
                              void* d_out, int out_size, void* d_ws, size_t ws_size,
                              hipStream_t stream) {
    const int*   user_idx = (const int*)d_in[0];
    const int*   loc_idx  = (const int*)d_in[1];
    const int*   pos_idx  = (const int*)d_in[2];
    const int*   neg_idx  = (const int*)d_in[3];
    const float* ucat     = (const float*)d_in[4];
    const float* utxt     = (const float*)d_in[5];
    const float* lcat     = (const float*)d_in[6];
    const float* ltxt     = (const float*)d_in[7];
    const float* sbert    = (const float*)d_in[8];
    const float* mh       = (const float*)d_in[9];
    const float* Wc1      = (const float*)d_in[10];
    const float* bc1      = (const float*)d_in[11];
    const float* Wc2      = (const float*)d_in[12];
    const float* bc2      = (const float*)d_in[13];
    const float* Wt1      = (const float*)d_in[14];
    const float* bt1      = (const float*)d_in[15];
    const float* Wt2      = (const float*)d_in[16];
    const float* bt2      = (const float*)d_in[17];

    const int Bn     = in_sizes[0];
    const int nbooks = in_sizes[8] / SBD;          // 100000

    char* ws = (char*)d_ws;
    float* E = (float*)ws;
    size_t off = ((size_t)nbooks * EMB * 4 + 255) & ~(size_t)255;
    char* iT1 = ws + off;  off += 196608;
    char* iK2 = ws + off;  off += 53248;

    hipLaunchKernelGGL(prep_weights, dim3(64), dim3(256), 0, stream,
                       Wt1, Wt2, Wc1, Wc2, iT1, iK2);

    const int nblocks = (nbooks + 127) / 128;      // 782
    hipLaunchKernelGGL(encode_fused, dim3(nblocks), dim3(512), 0, stream,
                       sbert, mh, iT1, iK2, bt1, bt2, bc1, bc2, E, nbooks);

    const int nblocksB = (Bn + 15) / 16;
    hipLaunchKernelGGL(score_kernel, dim3(nblocksB), dim3(256), 0, stream,
                       user_idx, loc_idx, pos_idx, neg_idx,
                       ucat, utxt, lcat, ltxt, E, (float*)d_out, Bn);
}